// Round 1
// baseline (1120.552 us; speedup 1.0000x reference)
//
#include <hip/hip_runtime.h>
#include <stdint.h>

#define BTOK 32768
#define DIN 256
#define DHID 512
#define DOUT 256
#define NEXP 16

typedef __attribute__((ext_vector_type(8))) short bf16x8;
typedef __attribute__((ext_vector_type(4))) float f32x4;

__device__ __forceinline__ unsigned short f2bf(float f){
  unsigned u = __builtin_bit_cast(unsigned, f);
  u = u + 0x7FFFu + ((u >> 16) & 1u);      // RNE, finite inputs only
  return (unsigned short)(u >> 16);
}
__device__ __forceinline__ float bf2f(unsigned short h){
  return __builtin_bit_cast(float, (unsigned)h << 16);
}

// ---------------- transpose + f32->bf16 convert:  src[e][R][C] -> dst[e][C][R]
__global__ __launch_bounds__(256) void transpose_cvt(const float* __restrict__ src,
                                                     unsigned short* __restrict__ dst,
                                                     int R, int C){
  __shared__ float t[32][33];
  int e = blockIdx.z, r0 = blockIdx.y * 32, c0 = blockIdx.x * 32;
  int lx = threadIdx.x & 31, ly = threadIdx.x >> 5;
  const float* s = src + (size_t)e * R * C;
  unsigned short* d = dst + (size_t)e * R * C;
#pragma unroll
  for (int i = 0; i < 4; i++){ int r = ly + i * 8; t[r][lx] = s[(size_t)(r0 + r) * C + c0 + lx]; }
  __syncthreads();
#pragma unroll
  for (int i = 0; i < 4; i++){ int r = ly + i * 8; d[(size_t)(c0 + r) * R + r0 + lx] = f2bf(t[lx][r]); }
}

// ---------------- gating: logits -> top2 -> weights; also emits x_bf16
__global__ __launch_bounds__(256) void gating_kernel(const float* __restrict__ x,
                                                     const float* __restrict__ Wg,
                                                     const float* __restrict__ bg,
                                                     unsigned short* __restrict__ x_bf,
                                                     int* __restrict__ top_idx,
                                                     float* __restrict__ top_w,
                                                     int* __restrict__ counts){
  __shared__ float WgT[16][256];   // transposed gate weights
  int tid = threadIdx.x;
#pragma unroll
  for (int e = 0; e < 16; e++) WgT[e][tid] = Wg[tid * 16 + e];
  __syncthreads();
  int wid = tid >> 6, lane = tid & 63;
  int tok = blockIdx.x * 4 + wid;
  const float4 xv = *(const float4*)(x + (size_t)tok * DIN + lane * 4);
  ushort4 xb; xb.x = f2bf(xv.x); xb.y = f2bf(xv.y); xb.z = f2bf(xv.z); xb.w = f2bf(xv.w);
  *(ushort4*)(x_bf + (size_t)tok * DIN + lane * 4) = xb;
  float logit[16];
#pragma unroll
  for (int e = 0; e < 16; e++){
    const float4 wv = *(const float4*)(&WgT[e][lane * 4]);
    float v = xv.x * wv.x + xv.y * wv.y + xv.z * wv.z + xv.w * wv.w;
#pragma unroll
    for (int off = 32; off; off >>= 1) v += __shfl_xor(v, off, 64);
    logit[e] = v + bg[e];
  }
  if (lane == 0){
    int i1 = 0; float v1 = logit[0];
#pragma unroll
    for (int e = 1; e < 16; e++) if (logit[e] > v1){ v1 = logit[e]; i1 = e; }
    int i2 = -1; float v2 = -3.4e38f;
#pragma unroll
    for (int e = 0; e < 16; e++) if (e != i1 && logit[e] > v2){ v2 = logit[e]; i2 = e; }
    float t = expf(v2 - v1);               // <= 1
    float w1 = 1.0f / (1.0f + t);
    float w2 = t / (1.0f + t);
    top_idx[tok * 2] = i1; top_idx[tok * 2 + 1] = i2;
    top_w[tok * 2] = w1;  top_w[tok * 2 + 1] = w2;
    atomicAdd(&counts[i1], 1); atomicAdd(&counts[i2], 1);
  }
}

// ---------------- prefix sum + block map (serial, tiny)
__global__ void prefix_kernel(const int* __restrict__ counts, int* __restrict__ offsets,
                              int* __restrict__ cursor, int* __restrict__ bm_e,
                              int* __restrict__ bm_start, int* __restrict__ bm_end,
                              int* __restrict__ nblocks){
  if (threadIdx.x == 0 && blockIdx.x == 0){
    int off = 0, nb = 0;
    for (int e = 0; e < 16; e++){
      offsets[e] = off; cursor[e] = off;
      int c = counts[e]; int end = off + c;
      for (int b = 0; b * 64 < c; b++){ bm_e[nb] = e; bm_start[nb] = off + b * 64; bm_end[nb] = end; nb++; }
      off = end;
    }
    nblocks[0] = nb;
  }
}

// ---------------- scatter token->expert-sorted pair list
__global__ __launch_bounds__(256) void scatter_kernel(const int* __restrict__ top_idx,
                                                      const float* __restrict__ top_w,
                                                      int* __restrict__ cursor,
                                                      int* __restrict__ pair_tok,
                                                      float* __restrict__ pair_w,
                                                      int* __restrict__ pair_slot){
  int t = blockIdx.x * 256 + threadIdx.x;
  if (t >= BTOK) return;
#pragma unroll
  for (int k = 0; k < 2; k++){
    int e = top_idx[t * 2 + k];
    int p = atomicAdd(&cursor[e], 1);
    pair_tok[p] = t; pair_w[p] = top_w[t * 2 + k]; pair_slot[t * 2 + k] = p;
  }
}

// ---------------- fused 2-layer expert MLP, 64 pairs/block, 4 waves, 16x16x32 bf16 MFMA
__global__ __launch_bounds__(256) void moe_gemm_kernel(
    const unsigned short* __restrict__ x_bf,   // [B][256]
    const unsigned short* __restrict__ W1t,    // [E][512][256]  (n-major)
    const unsigned short* __restrict__ W2t,    // [E][256][512]  (n-major)
    const float* __restrict__ b1,              // [E][512]
    const float* __restrict__ b2,              // [E][256]
    const int* __restrict__ pair_tok, const float* __restrict__ pair_w,
    const int* __restrict__ bm_e, const int* __restrict__ bm_start,
    const int* __restrict__ bm_end, const int* __restrict__ nblocks,
    unsigned short* __restrict__ ypair){       // [65536][256] bf16
  int bid = blockIdx.x;
  if (bid >= nblocks[0]) return;
  int e = bm_e[bid], rs = bm_start[bid], re = bm_end[bid];

  __shared__ unsigned short xs[64 * 256];   // 32KB, swizzled
  __shared__ unsigned short w1s[64 * 64];   // 8KB,  swizzled   [n][k]
  __shared__ unsigned short hs[64 * 64];    // 8KB,  swizzled   [m][k]
  __shared__ int   tokS[64];
  __shared__ float wS[64];
  char* xsb = (char*)xs; char* w1b = (char*)w1s; char* hsb = (char*)hs;

  int tid = threadIdx.x;
  if (tid < 64){
    int g = rs + tid;
    bool valid = g < re;
    tokS[tid] = valid ? pair_tok[g] : 0;
    wS[tid]   = valid ? pair_w[g] : 0.0f;
  }
  __syncthreads();

  // stage x tile (64 rows x 256 bf16), XOR-swizzled rows of 512B
#pragma unroll
  for (int it = 0; it < 8; it++){
    int flat = it * 256 + tid;
    int row = flat >> 5, ch = flat & 31;
    uint4 v = *(const uint4*)(x_bf + (size_t)tokS[row] * DIN + ch * 8);
    *(uint4*)(xsb + ((row * 512 + ch * 16) ^ ((row & 7) << 4))) = v;
  }

  int wid = tid >> 6, lane = tid & 63, lr = lane & 15, lh = lane >> 4;
  f32x4 acc[4][4];
#pragma unroll
  for (int i = 0; i < 4; i++)
#pragma unroll
    for (int j = 0; j < 4; j++) acc[i][j] = (f32x4){0.f, 0.f, 0.f, 0.f};

  const unsigned short* W1e = W1t + (size_t)e * DHID * DIN;
  const unsigned short* W2e = W2t + (size_t)e * DOUT * DHID;

  for (int c = 0; c < 8; c++){             // hid chunks of 64
    f32x4 hacc[4];
#pragma unroll
    for (int i = 0; i < 4; i++) hacc[i] = (f32x4){0.f, 0.f, 0.f, 0.f};

    for (int kb = 0; kb < 4; kb++){        // d_in in steps of 64
      __syncthreads();                     // protect w1s (and hs at chunk entry)
#pragma unroll
      for (int it = 0; it < 2; it++){
        int flat = it * 256 + tid;
        int row = flat >> 3, ch = flat & 7;
        uint4 v = *(const uint4*)(W1e + (size_t)(c * 64 + row) * DIN + kb * 64 + ch * 8);
        *(uint4*)(w1b + ((row * 128 + ch * 16) ^ ((row & 7) << 4))) = v;
      }
      __syncthreads();
      int arow = 16 * wid + lr;
#pragma unroll
      for (int ks = 0; ks < 2; ks++){
        int kk = kb * 64 + ks * 32 + lh * 8;
        bf16x8 a = *(const bf16x8*)(xsb + ((arow * 512 + kk * 2) ^ ((arow & 7) << 4)));
#pragma unroll
        for (int nt = 0; nt < 4; nt++){
          int bn = nt * 16 + lr, bk = ks * 32 + lh * 8;
          bf16x8 b = *(const bf16x8*)(w1b + ((bn * 128 + bk * 2) ^ ((bn & 7) << 4)));
          hacc[nt] = __builtin_amdgcn_mfma_f32_16x16x32_bf16(a, b, hacc[nt], 0, 0, 0);
        }
      }
    }
    // epilogue A: relu(h + b1) -> bf16 -> hs   (wave w owns rows 16w..16w+15)
#pragma unroll
    for (int nt = 0; nt < 4; nt++){
      float b1v = b1[e * DHID + c * 64 + nt * 16 + lr];
#pragma unroll
      for (int r = 0; r < 4; r++){
        int hrow = 16 * wid + lh * 4 + r;
        float v = hacc[nt][r] + b1v;
        v = fmaxf(v, 0.0f);
        int hcol = nt * 16 + lr;
        *(unsigned short*)(hsb + ((hrow * 128 + hcol * 2) ^ ((hrow & 7) << 4))) = f2bf(v);
      }
    }
    __syncthreads();
    // phase B: y += h[64x64] @ W2chunk ; wave w owns output cols 64w..64w+63
#pragma unroll
    for (int ks = 0; ks < 2; ks++){
      bf16x8 af[4];
#pragma unroll
      for (int mt = 0; mt < 4; mt++){
        int hr = mt * 16 + lr, hk = ks * 32 + lh * 8;
        af[mt] = *(const bf16x8*)(hsb + ((hr * 128 + hk * 2) ^ ((hr & 7) << 4)));
      }
#pragma unroll
      for (int nt = 0; nt < 4; nt++){
        int n = 64 * wid + nt * 16 + lr, kg = c * 64 + ks * 32 + lh * 8;
        bf16x8 b = *(const bf16x8*)(W2e + (size_t)n * DHID + kg);   // global, L2-hot
#pragma unroll
        for (int mt = 0; mt < 4; mt++)
          acc[mt][nt] = __builtin_amdgcn_mfma_f32_16x16x32_bf16(af[mt], b, acc[mt][nt], 0, 0, 0);
      }
    }
  }

  // epilogue: fold gate weight + b2, store per-pair bf16 rows
#pragma unroll
  for (int nt = 0; nt < 4; nt++){
    int col = 64 * wid + nt * 16 + lr;
    float b2v = b2[e * DOUT + col];
#pragma unroll
    for (int mt = 0; mt < 4; mt++){
#pragma unroll
      for (int r = 0; r < 4; r++){
        int row = mt * 16 + lh * 4 + r;
        int prow = rs + row;
        if (prow < re){
          float val = wS[row] * (acc[mt][nt][r] + b2v);
          ypair[(size_t)prow * DOUT + col] = f2bf(val);
        }
      }
    }
  }
}

// ---------------- combine two pair rows per token
__global__ __launch_bounds__(256) void combine_kernel(const unsigned short* __restrict__ yp,
                                                      const int* __restrict__ pair_slot,
                                                      float* __restrict__ out){
  int idx = blockIdx.x * 256 + threadIdx.x;   // BTOK*64 threads, 4 cols each
  int t = idx >> 6;
  int c4 = (idx & 63) << 2;
  int s0 = pair_slot[t * 2], s1 = pair_slot[t * 2 + 1];
  ushort4 a = *(const ushort4*)(yp + (size_t)s0 * DOUT + c4);
  ushort4 b = *(const ushort4*)(yp + (size_t)s1 * DOUT + c4);
  float4 o;
  o.x = bf2f(a.x) + bf2f(b.x);
  o.y = bf2f(a.y) + bf2f(b.y);
  o.z = bf2f(a.z) + bf2f(b.z);
  o.w = bf2f(a.w) + bf2f(b.w);
  *(float4*)(out + (size_t)t * DOUT + c4) = o;
}

extern "C" void kernel_launch(void* const* d_in, const int* in_sizes, int n_in,
                              void* d_out, int out_size, void* d_ws, size_t ws_size,
                              hipStream_t stream){
  (void)in_sizes; (void)n_in; (void)out_size; (void)ws_size;
  const float* x  = (const float*)d_in[0];
  const float* Wg = (const float*)d_in[1];
  const float* bg = (const float*)d_in[2];
  const float* W1 = (const float*)d_in[3];
  const float* b1 = (const float*)d_in[4];
  const float* W2 = (const float*)d_in[5];
  const float* b2 = (const float*)d_in[6];
  float* out = (float*)d_out;
  char* ws = (char*)d_ws;

  unsigned short* x_bf  = (unsigned short*)(ws);                 // 16,777,216
  unsigned short* W1t   = (unsigned short*)(ws + 16777216);      //  4,194,304
  unsigned short* W2t   = (unsigned short*)(ws + 20971520);      //  4,194,304
  unsigned short* ypair = (unsigned short*)(ws + 25165824);      // 33,554,432
  int*   top_idx  = (int*)  (ws + 58720256);
  float* top_w    = (float*)(ws + 58982400);
  int*   pair_tok = (int*)  (ws + 59244544);
  float* pair_w   = (float*)(ws + 59506688);
  int*   pair_slot= (int*)  (ws + 59768832);
  int*   counts   = (int*)  (ws + 60030976);
  int*   offsets  = (int*)  (ws + 60031040);
  int*   cursor   = (int*)  (ws + 60031104);
  int*   nblocks  = (int*)  (ws + 60031168);
  int*   bm_e     = (int*)  (ws + 60031232);
  int*   bm_start = (int*)  (ws + 60035584);
  int*   bm_end   = (int*)  (ws + 60039936);

  hipMemsetAsync(counts, 0, 64, stream);
  transpose_cvt<<<dim3(16, 8, 16), 256, 0, stream>>>(W1, W1t, 256, 512);
  transpose_cvt<<<dim3(8, 16, 16), 256, 0, stream>>>(W2, W2t, 512, 256);
  gating_kernel<<<8192, 256, 0, stream>>>(x, Wg, bg, x_bf, top_idx, top_w, counts);
  prefix_kernel<<<1, 64, 0, stream>>>(counts, offsets, cursor, bm_e, bm_start, bm_end, nblocks);
  scatter_kernel<<<128, 256, 0, stream>>>(top_idx, top_w, cursor, pair_tok, pair_w, pair_slot);
  moe_gemm_kernel<<<1040, 256, 0, stream>>>(x_bf, W1t, W2t, b1, b2, pair_tok, pair_w,
                                            bm_e, bm_start, bm_end, nblocks, ypair);
  combine_kernel<<<8192, 256, 0, stream>>>(ypair, pair_slot, out);
}

// Round 2
// 237.805 us; speedup vs baseline: 4.7121x; 4.7121x over previous
//
#include <hip/hip_runtime.h>
#include <stdint.h>

#define BTOK 32768
#define DIN 256
#define DHID 512
#define DOUT 256
#define NEXP 16

typedef __attribute__((ext_vector_type(8))) short bf16x8;
typedef __attribute__((ext_vector_type(4))) float f32x4;

__device__ __forceinline__ unsigned short f2bf(float f){
  unsigned u = __builtin_bit_cast(unsigned, f);
  u = u + 0x7FFFu + ((u >> 16) & 1u);      // RNE, finite inputs only
  return (unsigned short)(u >> 16);
}
__device__ __forceinline__ float bf2f(unsigned short h){
  return __builtin_bit_cast(float, (unsigned)h << 16);
}

// ---------------- transpose + f32->bf16 convert:  src[e][R][C] -> dst[e][C][R]
__global__ __launch_bounds__(256) void transpose_cvt(const float* __restrict__ src,
                                                     unsigned short* __restrict__ dst,
                                                     int R, int C){
  __shared__ float t[32][33];
  int e = blockIdx.z, r0 = blockIdx.y * 32, c0 = blockIdx.x * 32;
  int lx = threadIdx.x & 31, ly = threadIdx.x >> 5;
  const float* s = src + (size_t)e * R * C;
  unsigned short* d = dst + (size_t)e * R * C;
#pragma unroll
  for (int i = 0; i < 4; i++){ int r = ly + i * 8; t[r][lx] = s[(size_t)(r0 + r) * C + c0 + lx]; }
  __syncthreads();
#pragma unroll
  for (int i = 0; i < 4; i++){ int r = ly + i * 8; d[(size_t)(c0 + r) * R + r0 + lx] = f2bf(t[lx][r]); }
}

// ---------------- gating: 512 blocks x 64 tokens; LDS-aggregated histogram
__global__ __launch_bounds__(256) void gating_kernel(const float* __restrict__ x,
                                                     const float* __restrict__ Wg,
                                                     const float* __restrict__ bg,
                                                     unsigned short* __restrict__ x_bf,
                                                     int* __restrict__ top_idx,
                                                     float* __restrict__ top_w,
                                                     int* __restrict__ counts){
  __shared__ float WgT[16][256];   // transposed gate weights
  __shared__ int hist[16];
  int tid = threadIdx.x;
#pragma unroll
  for (int j = 0; j < 4; j++){     // coalesced: thread reads 64B contiguous
    float4 wv = *(const float4*)(Wg + tid * 16 + j * 4);
    WgT[j * 4 + 0][tid] = wv.x; WgT[j * 4 + 1][tid] = wv.y;
    WgT[j * 4 + 2][tid] = wv.z; WgT[j * 4 + 3][tid] = wv.w;
  }
  if (tid < 16) hist[tid] = 0;
  __syncthreads();
  int wid = tid >> 6, lane = tid & 63;

  for (int t = 0; t < 16; t++){
    int tok = blockIdx.x * 64 + wid * 16 + t;
    const float4 xv = *(const float4*)(x + (size_t)tok * DIN + lane * 4);
    ushort4 xb; xb.x = f2bf(xv.x); xb.y = f2bf(xv.y); xb.z = f2bf(xv.z); xb.w = f2bf(xv.w);
    *(ushort4*)(x_bf + (size_t)tok * DIN + lane * 4) = xb;
    float logit[16];
#pragma unroll
    for (int e = 0; e < 16; e++){
      const float4 wv = *(const float4*)(&WgT[e][lane * 4]);
      float v = xv.x * wv.x + xv.y * wv.y + xv.z * wv.z + xv.w * wv.w;
#pragma unroll
      for (int off = 32; off; off >>= 1) v += __shfl_xor(v, off, 64);
      logit[e] = v + bg[e];
    }
    if (lane == 0){
      int i1 = 0; float v1 = logit[0];
#pragma unroll
      for (int e = 1; e < 16; e++) if (logit[e] > v1){ v1 = logit[e]; i1 = e; }
      int i2 = -1; float v2 = -3.4e38f;
#pragma unroll
      for (int e = 0; e < 16; e++) if (e != i1 && logit[e] > v2){ v2 = logit[e]; i2 = e; }
      float tt = expf(v2 - v1);               // <= 1
      float w1 = 1.0f / (1.0f + tt);
      float w2 = tt / (1.0f + tt);
      top_idx[tok * 2] = i1; top_idx[tok * 2 + 1] = i2;
      top_w[tok * 2] = w1;  top_w[tok * 2 + 1] = w2;
      atomicAdd(&hist[i1], 1); atomicAdd(&hist[i2], 1);   // LDS atomics
    }
  }
  __syncthreads();
  if (tid < 16) atomicAdd(&counts[tid], hist[tid]);       // 16 global atomics/block
}

// ---------------- prefix sum + block map (serial, tiny)
__global__ void prefix_kernel(const int* __restrict__ counts, int* __restrict__ offsets,
                              int* __restrict__ cursor, int* __restrict__ bm_e,
                              int* __restrict__ bm_start, int* __restrict__ bm_end,
                              int* __restrict__ nblocks){
  if (threadIdx.x == 0 && blockIdx.x == 0){
    int off = 0, nb = 0;
    for (int e = 0; e < 16; e++){
      offsets[e] = off; cursor[e] = off;
      int c = counts[e]; int end = off + c;
      for (int b = 0; b * 64 < c; b++){ bm_e[nb] = e; bm_start[nb] = off + b * 64; bm_end[nb] = end; nb++; }
      off = end;
    }
    nblocks[0] = nb;
  }
}

// ---------------- scatter: block-aggregated chunk reservation, LDS ranks
__global__ __launch_bounds__(256) void scatter_kernel(const int* __restrict__ top_idx,
                                                      const float* __restrict__ top_w,
                                                      int* __restrict__ cursor,
                                                      int* __restrict__ pair_tok,
                                                      float* __restrict__ pair_w,
                                                      int* __restrict__ pair_slot){
  __shared__ int hist[16], base[16], rank[16];
  int tid = threadIdx.x;
  if (tid < 16){ hist[tid] = 0; rank[tid] = 0; }
  __syncthreads();
  int t = blockIdx.x * 256 + tid;
  int e0 = top_idx[t * 2], e1 = top_idx[t * 2 + 1];
  float w0 = top_w[t * 2], w1 = top_w[t * 2 + 1];
  atomicAdd(&hist[e0], 1); atomicAdd(&hist[e1], 1);
  __syncthreads();
  if (tid < 16) base[tid] = atomicAdd(&cursor[tid], hist[tid]);  // 16 global atomics/block
  __syncthreads();
  int r0 = atomicAdd(&rank[e0], 1);
  int p0 = base[e0] + r0;
  pair_tok[p0] = t; pair_w[p0] = w0; pair_slot[t * 2] = p0;
  int r1 = atomicAdd(&rank[e1], 1);
  int p1 = base[e1] + r1;
  pair_tok[p1] = t; pair_w[p1] = w1; pair_slot[t * 2 + 1] = p1;
}

// ---------------- fused 2-layer expert MLP, 64 pairs/block, 4 waves, 16x16x32 bf16 MFMA
__global__ __launch_bounds__(256) void moe_gemm_kernel(
    const unsigned short* __restrict__ x_bf,   // [B][256]
    const unsigned short* __restrict__ W1t,    // [E][512][256]  (n-major)
    const unsigned short* __restrict__ W2t,    // [E][256][512]  (n-major)
    const float* __restrict__ b1,              // [E][512]
    const float* __restrict__ b2,              // [E][256]
    const int* __restrict__ pair_tok, const float* __restrict__ pair_w,
    const int* __restrict__ bm_e, const int* __restrict__ bm_start,
    const int* __restrict__ bm_end, const int* __restrict__ nblocks,
    unsigned short* __restrict__ ypair){       // [65536][256] bf16
  int bid = blockIdx.x;
  if (bid >= nblocks[0]) return;
  int e = bm_e[bid], rs = bm_start[bid], re = bm_end[bid];

  __shared__ unsigned short xs[64 * 256];   // 32KB, swizzled
  __shared__ unsigned short w1s[64 * 64];   // 8KB,  swizzled   [n][k]
  __shared__ unsigned short hs[64 * 64];    // 8KB,  swizzled   [m][k]
  __shared__ int   tokS[64];
  __shared__ float wS[64];
  char* xsb = (char*)xs; char* w1b = (char*)w1s; char* hsb = (char*)hs;

  int tid = threadIdx.x;
  if (tid < 64){
    int g = rs + tid;
    bool valid = g < re;
    tokS[tid] = valid ? pair_tok[g] : 0;
    wS[tid]   = valid ? pair_w[g] : 0.0f;
  }
  __syncthreads();

  // stage x tile (64 rows x 256 bf16), XOR-swizzled rows of 512B
#pragma unroll
  for (int it = 0; it < 8; it++){
    int flat = it * 256 + tid;
    int row = flat >> 5, ch = flat & 31;
    uint4 v = *(const uint4*)(x_bf + (size_t)tokS[row] * DIN + ch * 8);
    *(uint4*)(xsb + ((row * 512 + ch * 16) ^ ((row & 7) << 4))) = v;
  }

  int wid = tid >> 6, lane = tid & 63, lr = lane & 15, lh = lane >> 4;
  f32x4 acc[4][4];
#pragma unroll
  for (int i = 0; i < 4; i++)
#pragma unroll
    for (int j = 0; j < 4; j++) acc[i][j] = (f32x4){0.f, 0.f, 0.f, 0.f};

  const unsigned short* W1e = W1t + (size_t)e * DHID * DIN;
  const unsigned short* W2e = W2t + (size_t)e * DOUT * DHID;

  for (int c = 0; c < 8; c++){             // hid chunks of 64
    f32x4 hacc[4];
#pragma unroll
    for (int i = 0; i < 4; i++) hacc[i] = (f32x4){0.f, 0.f, 0.f, 0.f};

    for (int kb = 0; kb < 4; kb++){        // d_in in steps of 64
      __syncthreads();                     // protect w1s (and hs at chunk entry)
#pragma unroll
      for (int it = 0; it < 2; it++){
        int flat = it * 256 + tid;
        int row = flat >> 3, ch = flat & 7;
        uint4 v = *(const uint4*)(W1e + (size_t)(c * 64 + row) * DIN + kb * 64 + ch * 8);
        *(uint4*)(w1b + ((row * 128 + ch * 16) ^ ((row & 7) << 4))) = v;
      }
      __syncthreads();
      int arow = 16 * wid + lr;
#pragma unroll
      for (int ks = 0; ks < 2; ks++){
        int kk = kb * 64 + ks * 32 + lh * 8;
        bf16x8 a = *(const bf16x8*)(xsb + ((arow * 512 + kk * 2) ^ ((arow & 7) << 4)));
#pragma unroll
        for (int nt = 0; nt < 4; nt++){
          int bn = nt * 16 + lr, bk = ks * 32 + lh * 8;
          bf16x8 b = *(const bf16x8*)(w1b + ((bn * 128 + bk * 2) ^ ((bn & 7) << 4)));
          hacc[nt] = __builtin_amdgcn_mfma_f32_16x16x32_bf16(a, b, hacc[nt], 0, 0, 0);
        }
      }
    }
    // epilogue A: relu(h + b1) -> bf16 -> hs   (wave w owns rows 16w..16w+15)
#pragma unroll
    for (int nt = 0; nt < 4; nt++){
      float b1v = b1[e * DHID + c * 64 + nt * 16 + lr];
#pragma unroll
      for (int r = 0; r < 4; r++){
        int hrow = 16 * wid + lh * 4 + r;
        float v = hacc[nt][r] + b1v;
        v = fmaxf(v, 0.0f);
        int hcol = nt * 16 + lr;
        *(unsigned short*)(hsb + ((hrow * 128 + hcol * 2) ^ ((hrow & 7) << 4))) = f2bf(v);
      }
    }
    __syncthreads();
    // phase B: y += h[64x64] @ W2chunk ; wave w owns output cols 64w..64w+63
#pragma unroll
    for (int ks = 0; ks < 2; ks++){
      bf16x8 af[4];
#pragma unroll
      for (int mt = 0; mt < 4; mt++){
        int hr = mt * 16 + lr, hk = ks * 32 + lh * 8;
        af[mt] = *(const bf16x8*)(hsb + ((hr * 128 + hk * 2) ^ ((hr & 7) << 4)));
      }
#pragma unroll
      for (int nt = 0; nt < 4; nt++){
        int n = 64 * wid + nt * 16 + lr, kg = c * 64 + ks * 32 + lh * 8;
        bf16x8 b = *(const bf16x8*)(W2e + (size_t)n * DHID + kg);   // global, L2-hot
#pragma unroll
        for (int mt = 0; mt < 4; mt++)
          acc[mt][nt] = __builtin_amdgcn_mfma_f32_16x16x32_bf16(af[mt], b, acc[mt][nt], 0, 0, 0);
      }
    }
  }

  // epilogue: fold gate weight + b2, store per-pair bf16 rows
#pragma unroll
  for (int nt = 0; nt < 4; nt++){
    int col = 64 * wid + nt * 16 + lr;
    float b2v = b2[e * DOUT + col];
#pragma unroll
    for (int mt = 0; mt < 4; mt++){
#pragma unroll
      for (int r = 0; r < 4; r++){
        int row = mt * 16 + lh * 4 + r;
        int prow = rs + row;
        if (prow < re){
          float val = wS[row] * (acc[mt][nt][r] + b2v);
          ypair[(size_t)prow * DOUT + col] = f2bf(val);
        }
      }
    }
  }
}

// ---------------- combine two pair rows per token
__global__ __launch_bounds__(256) void combine_kernel(const unsigned short* __restrict__ yp,
                                                      const int* __restrict__ pair_slot,
                                                      float* __restrict__ out){
  int idx = blockIdx.x * 256 + threadIdx.x;   // BTOK*64 threads, 4 cols each
  int t = idx >> 6;
  int c4 = (idx & 63) << 2;
  int s0 = pair_slot[t * 2], s1 = pair_slot[t * 2 + 1];
  ushort4 a = *(const ushort4*)(yp + (size_t)s0 * DOUT + c4);
  ushort4 b = *(const ushort4*)(yp + (size_t)s1 * DOUT + c4);
  float4 o;
  o.x = bf2f(a.x) + bf2f(b.x);
  o.y = bf2f(a.y) + bf2f(b.y);
  o.z = bf2f(a.z) + bf2f(b.z);
  o.w = bf2f(a.w) + bf2f(b.w);
  *(float4*)(out + (size_t)t * DOUT + c4) = o;
}

extern "C" void kernel_launch(void* const* d_in, const int* in_sizes, int n_in,
                              void* d_out, int out_size, void* d_ws, size_t ws_size,
                              hipStream_t stream){
  (void)in_sizes; (void)n_in; (void)out_size; (void)ws_size;
  const float* x  = (const float*)d_in[0];
  const float* Wg = (const float*)d_in[1];
  const float* bg = (const float*)d_in[2];
  const float* W1 = (const float*)d_in[3];
  const float* b1 = (const float*)d_in[4];
  const float* W2 = (const float*)d_in[5];
  const float* b2 = (const float*)d_in[6];
  float* out = (float*)d_out;
  char* ws = (char*)d_ws;

  unsigned short* x_bf  = (unsigned short*)(ws);                 // 16,777,216
  unsigned short* W1t   = (unsigned short*)(ws + 16777216);      //  4,194,304
  unsigned short* W2t   = (unsigned short*)(ws + 20971520);      //  4,194,304
  unsigned short* ypair = (unsigned short*)(ws + 25165824);      // 33,554,432
  int*   top_idx  = (int*)  (ws + 58720256);
  float* top_w    = (float*)(ws + 58982400);
  int*   pair_tok = (int*)  (ws + 59244544);
  float* pair_w   = (float*)(ws + 59506688);
  int*   pair_slot= (int*)  (ws + 59768832);
  int*   counts   = (int*)  (ws + 60030976);
  int*   offsets  = (int*)  (ws + 60031040);
  int*   cursor   = (int*)  (ws + 60031104);
  int*   nblocks  = (int*)  (ws + 60031168);
  int*   bm_e     = (int*)  (ws + 60031232);
  int*   bm_start = (int*)  (ws + 60035584);
  int*   bm_end   = (int*)  (ws + 60039936);

  hipMemsetAsync(counts, 0, 64, stream);
  transpose_cvt<<<dim3(16, 8, 16), 256, 0, stream>>>(W1, W1t, 256, 512);
  transpose_cvt<<<dim3(8, 16, 16), 256, 0, stream>>>(W2, W2t, 512, 256);
  gating_kernel<<<512, 256, 0, stream>>>(x, Wg, bg, x_bf, top_idx, top_w, counts);
  prefix_kernel<<<1, 64, 0, stream>>>(counts, offsets, cursor, bm_e, bm_start, bm_end, nblocks);
  scatter_kernel<<<128, 256, 0, stream>>>(top_idx, top_w, cursor, pair_tok, pair_w, pair_slot);
  moe_gemm_kernel<<<1040, 256, 0, stream>>>(x_bf, W1t, W2t, b1, b2, pair_tok, pair_w,
                                            bm_e, bm_start, bm_end, nblocks, ypair);
  combine_kernel<<<8192, 256, 0, stream>>>(ypair, pair_slot, out);
}